// Round 2
// baseline (191.392 us; speedup 1.0000x reference)
//
#include <hip/hip_runtime.h>

// LearnableDCT: x (32,3,512,512) f32, basis (64,64) f32
// out (32, 192, 64, 64) f32 : out[b][c*64+k][hb][wb] = sum_n basis[k][n] * block[n]
// block[n=i*8+j] = x[b][c][hb*8+i][wb*8+j]
//
// Thread = (block, khalf): each thread computes 32 of the 64 k outputs for
// one 8x8 block. lane == wb so x loads and out stores are coalesced along w.
// khalf split doubles wave count (12/SIMD demand vs ~6 resident) for latency
// hiding; the two khalf waves in a WG share the same 16KB x row-block (L1 hit).

__global__ __launch_bounds__(256) void dct_kernel(
    const float* __restrict__ x,
    const float* __restrict__ basis,
    float* __restrict__ out)
{
    const int tid   = blockIdx.x * 256 + threadIdx.x;
    const int wb    = tid & 63;
    const int khalf = (tid >> 6) & 1;
    const int hbc   = tid >> 7;        // hb + bc*64
    const int hb    = hbc & 63;
    const int bc    = hbc >> 6;        // 0..95

    // x base for this block: bc*512*512 + (hb*8)*512 + wb*8
    const float* xp = x + ((size_t)bc << 18) + ((size_t)hb << 12) + (wb << 3);

    // load 8x8 block into registers (16x float4, statically indexed)
    float xr[64];
    #pragma unroll
    for (int i = 0; i < 8; ++i) {
        float4 a = *reinterpret_cast<const float4*>(xp + i * 512);
        float4 c = *reinterpret_cast<const float4*>(xp + i * 512 + 4);
        xr[i * 8 + 0] = a.x; xr[i * 8 + 1] = a.y;
        xr[i * 8 + 2] = a.z; xr[i * 8 + 3] = a.w;
        xr[i * 8 + 4] = c.x; xr[i * 8 + 5] = c.y;
        xr[i * 8 + 6] = c.z; xr[i * 8 + 7] = c.w;
    }

    // out base: (bc*64 + k)*4096 + hb*64 + wb
    const int k0 = khalf << 5;
    const float* bk = basis + (k0 << 6);                 // wave-uniform -> s_loads
    float* op = out + ((size_t)bc << 18) + ((size_t)k0 << 12) + (hb << 6) + wb;

    #pragma unroll 4
    for (int k = 0; k < 32; ++k) {
        float a0 = 0.f, a1 = 0.f;
        #pragma unroll
        for (int n = 0; n < 64; n += 2) {
            a0 = fmaf(bk[n + 0], xr[n + 0], a0);
            a1 = fmaf(bk[n + 1], xr[n + 1], a1);
        }
        __builtin_nontemporal_store(a0 + a1, op);
        bk += 64;
        op += 4096;
    }
}

extern "C" void kernel_launch(void* const* d_in, const int* in_sizes, int n_in,
                              void* d_out, int out_size, void* d_ws, size_t ws_size,
                              hipStream_t stream) {
    const float* x     = (const float*)d_in[0];
    const float* basis = (const float*)d_in[1];
    float* out         = (float*)d_out;

    // threads = 32*3*64*64 blocks * 2 khalf = 786432 -> 3072 WGs of 256
    dct_kernel<<<dim3(3072), dim3(256), 0, stream>>>(x, basis, out);
}

// Round 3
// 55.626 us; speedup vs baseline: 3.4407x; 3.4407x over previous
//
#include <hip/hip_runtime.h>

// LearnableDCT: x (32,3,512,512) f32, basis (64,64) f32
// out (32, 192, 64, 64) f32 : out[b][c*64+k][hb][wb] = sum_n basis[k][n] * block[n]
// block[n=i*8+j] = x[b][c][hb*8+i][wb*8+j]
//
// One thread handles TWO 8x8 blocks: (bc, hb=h2, wb) and (bc, hb=h2+32, wb).
// Rationale (round-2 post-mortem): the k-loop streams one 256B basis row
// through the scalar cache per iteration; with 1 block/thread that is 4B of
// SMEM per FMA and the s_load latency dominates (VALUBusy 35%). Two blocks
// halve SMEM/FMA and double the independent FMA chains per basis row.
// `k` is a plain loop variable so `bk` stays provably wave-uniform -> s_loads
// (round 2 lost this by deriving k0 from threadIdx -> vector loads + spills).

__global__ __launch_bounds__(256, 2) void dct_kernel(
    const float* __restrict__ x,
    const float* __restrict__ basis,
    float* __restrict__ out)
{
    const int tid = blockIdx.x * 256 + threadIdx.x;
    const int wb  = tid & 63;          // lane == wb: coalesced x loads + stores
    const int h2  = (tid >> 6) & 31;   // hb0 = h2, hb1 = h2 + 32
    const int bc  = tid >> 11;         // 0..95

    // x base: bc*512*512 + (hb*8)*512 + wb*8 ; hb step = 4096 floats
    const float* xp0 = x + ((size_t)bc << 18) + ((size_t)h2 << 12) + (wb << 3);
    const float* xp1 = xp0 + (32 << 12);

    // load both 8x8 blocks into registers (statically indexed throughout)
    float xr0[64], xr1[64];
    #pragma unroll
    for (int i = 0; i < 8; ++i) {
        float4 a = *reinterpret_cast<const float4*>(xp0 + i * 512);
        float4 b = *reinterpret_cast<const float4*>(xp0 + i * 512 + 4);
        float4 c = *reinterpret_cast<const float4*>(xp1 + i * 512);
        float4 d = *reinterpret_cast<const float4*>(xp1 + i * 512 + 4);
        xr0[i*8+0]=a.x; xr0[i*8+1]=a.y; xr0[i*8+2]=a.z; xr0[i*8+3]=a.w;
        xr0[i*8+4]=b.x; xr0[i*8+5]=b.y; xr0[i*8+6]=b.z; xr0[i*8+7]=b.w;
        xr1[i*8+0]=c.x; xr1[i*8+1]=c.y; xr1[i*8+2]=c.z; xr1[i*8+3]=c.w;
        xr1[i*8+4]=d.x; xr1[i*8+5]=d.y; xr1[i*8+6]=d.z; xr1[i*8+7]=d.w;
    }

    // out base: (bc*64 + k)*4096 + hb*64 + wb ; k step = 4096 floats
    float* op0 = out + ((size_t)bc << 18) + (h2 << 6) + wb;
    float* op1 = op0 + (32 << 6);

    const float* bk = basis;
    #pragma unroll 1
    for (int k = 0; k < 64; ++k) {
        float a0=0.f, a1=0.f, a2=0.f, a3=0.f;
        float b0=0.f, b1=0.f, b2=0.f, b3=0.f;
        #pragma unroll
        for (int n = 0; n < 64; n += 4) {
            const float c0 = bk[n+0], c1 = bk[n+1], c2 = bk[n+2], c3 = bk[n+3];
            a0 = fmaf(c0, xr0[n+0], a0);  b0 = fmaf(c0, xr1[n+0], b0);
            a1 = fmaf(c1, xr0[n+1], a1);  b1 = fmaf(c1, xr1[n+1], b1);
            a2 = fmaf(c2, xr0[n+2], a2);  b2 = fmaf(c2, xr1[n+2], b2);
            a3 = fmaf(c3, xr0[n+3], a3);  b3 = fmaf(c3, xr1[n+3], b3);
        }
        __builtin_nontemporal_store((a0 + a1) + (a2 + a3), op0);
        __builtin_nontemporal_store((b0 + b1) + (b2 + b3), op1);
        bk  += 64;
        op0 += 4096;
        op1 += 4096;
    }
}

extern "C" void kernel_launch(void* const* d_in, const int* in_sizes, int n_in,
                              void* d_out, int out_size, void* d_ws, size_t ws_size,
                              hipStream_t stream) {
    const float* x     = (const float*)d_in[0];
    const float* basis = (const float*)d_in[1];
    float* out         = (float*)d_out;

    // threads = 96 bc * 32 h2 * 64 wb = 196608 -> 768 WGs of 256
    dct_kernel<<<dim3(768), dim3(256), 0, stream>>>(x, basis, out);
}